// Round 18
// baseline (195.795 us; speedup 1.0000x reference)
//
#include <hip/hip_runtime.h>
#include <hip/hip_bf16.h>

#define EPS_F 1e-5f

typedef __bf16 bf16x8 __attribute__((ext_vector_type(8)));
typedef float f32x4 __attribute__((ext_vector_type(4)));

static __device__ __forceinline__ unsigned int pack_bf16x2(float a, float b) {
    union { float f; unsigned int u; } ca, cb;
    ca.f = a; cb.f = b;
    unsigned int ua = (ca.u + 0x7fffu + ((ca.u >> 16) & 1u)) >> 16;
    unsigned int ub = (cb.u + 0x7fffu + ((cb.u >> 16) & 1u)) >> 16;
    return ua | (ub << 16);
}

// ---- setup: wbf[n][k] = bf16(proj_w[n][k] * norm_scale[k]), [48][4096] ----
__global__ void scale_weights(const float* __restrict__ w,
                              const float* __restrict__ ns,
                              unsigned int* __restrict__ wbf)
{
    const int i = (blockIdx.x * 256 + threadIdx.x) * 4;
    const float4 wv = *reinterpret_cast<const float4*>(w + i);
    const float4 nv = *reinterpret_cast<const float4*>(ns + (i & 4095));
    uint2 o;
    o.x = pack_bf16x2(wv.x * nv.x, wv.y * nv.y);
    o.y = pack_bf16x2(wv.z * nv.z, wv.w * nv.w);
    *reinterpret_cast<uint2*>(wbf + (i >> 1)) = o;
}

// ============ Fused: M-projection (MFMA) + 4x4 math + apply, one kernel =====
// 512 threads (8 waves), 8 tokens/block, 2048 blocks = 2x chip wave capacity.
// Queue-depth test vs R13 (identical per-wave workload: 16 ks, 4-ks pinned
// batches): 8 blocks/CU queue -> tail-fill + read/write phase overlap.
__global__ __launch_bounds__(512)
void fused_stream_mix(const float* __restrict__ streams,
                      const unsigned short* __restrict__ wbf,   // scaled bf16 W [48][4096]
                      const float* __restrict__ proj_b,
                      const float* __restrict__ out_scale,
                      float* __restrict__ out)
{
    __shared__ float red[8][3][8][16];    // [kpart][ntile][token][col] = 12 KB
    __shared__ float ssq_red[8][8];       // [kpart][token]

    const int tid  = threadIdx.x;
    const int wv   = tid >> 6;            // wave == K-part (0..7)
    const int lane = tid & 63;
    const size_t tok0 = (size_t)blockIdx.x * 8;

    // ---------- Phase 2: MFMA projection, 8-way split-K, 4-ks pinned batches ----------
    {
        const int r = lane & 7;           // token row (dup'd into rows 8..15)
        const int g = lane >> 4;          // k-subgroup
        const int koff = g * 8;
        const int bcol = lane & 15;       // B column (output n within tile)
        const int kbase = wv * 512;       // this wave's K eighth

        const float* ap = streams + (tok0 + r) * 4096 + kbase + koff;
        const unsigned short* wp = wbf + (size_t)bcol * 4096 + kbase + koff;

        f32x4 acc0 = {0.f, 0.f, 0.f, 0.f};
        f32x4 acc1 = acc0, acc2 = acc0;
        float ssq = 0.f;

        #pragma unroll 1
        for (int p = 0; p < 4; ++p) {
            // batch-issue this pass's 8 A-loads (HBM) + 12 B-loads (L2)
            f32x4 ar[8];
            bf16x8 br[12];
            #pragma unroll
            for (int q = 0; q < 4; ++q) {
                const int ks = p * 4 + q;
                ar[2 * q]     = *reinterpret_cast<const f32x4*>(ap + ks * 32);
                ar[2 * q + 1] = *reinterpret_cast<const f32x4*>(ap + ks * 32 + 4);
                br[3 * q]     = *reinterpret_cast<const bf16x8*>(wp + ks * 32);
                br[3 * q + 1] = *reinterpret_cast<const bf16x8*>(wp + 16 * 4096 + ks * 32);
                br[3 * q + 2] = *reinterpret_cast<const bf16x8*>(wp + 32 * 4096 + ks * 32);
            }
            asm volatile("" ::
                "v"(ar[0]), "v"(ar[1]), "v"(ar[2]), "v"(ar[3]),
                "v"(ar[4]), "v"(ar[5]), "v"(ar[6]), "v"(ar[7]),
                "v"(br[0]), "v"(br[1]), "v"(br[2]), "v"(br[3]),
                "v"(br[4]), "v"(br[5]), "v"(br[6]), "v"(br[7]),
                "v"(br[8]), "v"(br[9]), "v"(br[10]), "v"(br[11]));

            #pragma unroll
            for (int q = 0; q < 4; ++q) {
                const f32x4 a0 = ar[2 * q], a1 = ar[2 * q + 1];
                ssq = fmaf(a0[0], a0[0], ssq); ssq = fmaf(a0[1], a0[1], ssq);
                ssq = fmaf(a0[2], a0[2], ssq); ssq = fmaf(a0[3], a0[3], ssq);
                ssq = fmaf(a1[0], a1[0], ssq); ssq = fmaf(a1[1], a1[1], ssq);
                ssq = fmaf(a1[2], a1[2], ssq); ssq = fmaf(a1[3], a1[3], ssq);
                bf16x8 a;
                a[0] = (__bf16)a0[0]; a[1] = (__bf16)a0[1]; a[2] = (__bf16)a0[2]; a[3] = (__bf16)a0[3];
                a[4] = (__bf16)a1[0]; a[5] = (__bf16)a1[1]; a[6] = (__bf16)a1[2]; a[7] = (__bf16)a1[3];
                acc0 = __builtin_amdgcn_mfma_f32_16x16x32_bf16(a, br[3 * q],     acc0, 0, 0, 0);
                acc1 = __builtin_amdgcn_mfma_f32_16x16x32_bf16(a, br[3 * q + 1], acc1, 0, 0, 0);
                acc2 = __builtin_amdgcn_mfma_f32_16x16x32_bf16(a, br[3 * q + 2], acc2, 0, 0, 0);
            }
        }

        // ssq: lanes {l, l^16, l^32, l^48} cover the 4 k-subgroups of token r
        // (lane l and l^8 hold identical copies; reduce over g then write from lanes 0..7)
        ssq += __shfl_xor(ssq, 16, 64);
        ssq += __shfl_xor(ssq, 32, 64);
        if (lane < 8) ssq_red[wv][lane] = ssq;

        // D layout: col=lane&15 (=n), row=(lane>>4)*4+reg (=token; rows 0..7 valid)
        if (lane < 32) {
            const int col = lane & 15, rg = (lane >> 4) * 4;
            #pragma unroll
            for (int rr = 0; rr < 4; ++rr) {
                red[wv][0][rg + rr][col] = acc0[rr];
                red[wv][1][rg + rr][col] = acc1[rr];
                red[wv][2][rg + rr][col] = acc2[rr];
            }
        }
    }

    // ---------- Phase 3+4 setup: whole wave owns token wv ----------
    const int t = wv;
    const float* src = streams + (tok0 + t) * 4096;
    float* dst = out + (tok0 + t) * 4096;

    // issue first phase-4 load batch before the barrier; L2-hot, hides under
    // barrier wait + phase-3 math
    f32x4 px0 = *reinterpret_cast<const f32x4*>(src + lane * 4);
    f32x4 px1 = *reinterpret_cast<const f32x4*>(src + 1024 + lane * 4);
    f32x4 px2 = *reinterpret_cast<const f32x4*>(src + 2048 + lane * 4);
    f32x4 px3 = *reinterpret_cast<const f32x4*>(src + 3072 + lane * 4);
    asm volatile("" :: "v"(px0), "v"(px1), "v"(px2), "v"(px3));

    __syncthreads();   // the only barrier

    // ---------- Phase 3: build M in registers (redundant per wave) ----------
    float Mr[16];
    {
        float st = 0.f;
        #pragma unroll
        for (int kp = 0; kp < 8; ++kp) st += ssq_red[kp][t];
        const float invr = rsqrtf(st * (1.f / 4096.f) + EPS_F);

        #define REDUCE_TILE(tile, raw)                                             \
            {                                                                      \
                _Pragma("unroll")                                                  \
                for (int c4 = 0; c4 < 4; ++c4) {                                   \
                    f32x4 s = {0.f, 0.f, 0.f, 0.f};                                \
                    _Pragma("unroll")                                              \
                    for (int kp = 0; kp < 8; ++kp)                                 \
                        s += *reinterpret_cast<const f32x4*>(&red[kp][tile][t][c4 * 4]); \
                    const float4 pb = *reinterpret_cast<const float4*>(&proj_b[tile * 16 + c4 * 4]); \
                    raw[c4*4 + 0] = s[0] * invr + pb.x;                            \
                    raw[c4*4 + 1] = s[1] * invr + pb.y;                            \
                    raw[c4*4 + 2] = s[2] * invr + pb.z;                            \
                    raw[c4*4 + 3] = s[3] * invr + pb.w;                            \
                }                                                                  \
            }

        float c[4] = {0.f, 0.f, 0.f, 0.f};
        {
            float raw[16];
            REDUCE_TILE(0, raw)
            #pragma unroll
            for (int i = 0; i < 4; ++i) {
                const float a0 = raw[i*4+0], a1 = raw[i*4+1], a2 = raw[i*4+2], a3 = raw[i*4+3];
                const float m = fmaxf(fmaxf(a0, a1), fmaxf(a2, a3));
                const float e0 = expf(a0 - m), e1 = expf(a1 - m);
                const float e2 = expf(a2 - m), e3 = expf(a3 - m);
                const float inv = 1.f / (e0 + e1 + e2 + e3);
                c[0] = fmaf(e0, inv, c[0]); c[1] = fmaf(e1, inv, c[1]);
                c[2] = fmaf(e2, inv, c[2]); c[3] = fmaf(e3, inv, c[3]);
            }
            c[0] *= 0.25f; c[1] *= 0.25f; c[2] *= 0.25f; c[3] *= 0.25f;
        }

        float rs[4] = {0.f, 0.f, 0.f, 0.f};
        {
            float raw[16];
            REDUCE_TILE(1, raw)
            #pragma unroll
            for (int j = 0; j < 4; ++j) {
                const float b0 = raw[j], b1 = raw[4+j], b2 = raw[8+j], b3 = raw[12+j];
                const float m = fmaxf(fmaxf(b0, b1), fmaxf(b2, b3));
                const float e0 = expf(b0 - m), e1 = expf(b1 - m);
                const float e2 = expf(b2 - m), e3 = expf(b3 - m);
                const float inv = 1.f / (e0 + e1 + e2 + e3);
                rs[0] = fmaf(e0, inv, rs[0]); rs[1] = fmaf(e1, inv, rs[1]);
                rs[2] = fmaf(e2, inv, rs[2]); rs[3] = fmaf(e3, inv, rs[3]);
            }
        }

        float W[16], Y[16];
        {
            float raw[16];
            REDUCE_TILE(2, raw)
            #pragma unroll
            for (int i = 0; i < 4; ++i)
                #pragma unroll
                for (int j = 0; j < 4; ++j)
                    W[i*4+j] = raw[i*4+j] - raw[j*4+i];
        }
        #pragma unroll
        for (int i = 0; i < 16; ++i) Y[i] = 0.1f * W[i];
        Y[0] += 1.f; Y[5] += 1.f; Y[10] += 1.f; Y[15] += 1.f;
        #pragma unroll
        for (int it = 0; it < 2; ++it) {
            float T1[16];
            #pragma unroll
            for (int i = 0; i < 16; ++i) T1[i] = Y[i];
            T1[0] += 1.f; T1[5] += 1.f; T1[10] += 1.f; T1[15] += 1.f;
            float Yn[16];
            #pragma unroll
            for (int i = 0; i < 4; ++i)
                #pragma unroll
                for (int j = 0; j < 4; ++j) {
                    float s = W[i*4+0] * T1[0*4+j];
                    s = fmaf(W[i*4+1], T1[1*4+j], s);
                    s = fmaf(W[i*4+2], T1[2*4+j], s);
                    s = fmaf(W[i*4+3], T1[3*4+j], s);
                    Yn[i*4+j] = ((i == j) ? 1.f : 0.f) + 0.05f * s;
                }
            #pragma unroll
            for (int i = 0; i < 16; ++i) Y[i] = Yn[i];
        }

        const float os = out_scale[0];
        #pragma unroll
        for (int i = 0; i < 4; ++i)
            #pragma unroll
            for (int j = 0; j < 4; ++j)
                Mr[i*4+j] = Y[i*4+j] + os * rs[i] * c[j];
        #undef REDUCE_TILE
    }

    // ---------- Phase 4: out[t] = M @ streams[t], cache-hot re-read ----------
    #pragma unroll 2
    for (int cq = 0; cq < 4; ++cq) {
        const f32x4 x0 = px0, x1 = px1, x2 = px2, x3 = px3;
        if (cq < 3) {
            const int ncol = (cq + 1) * 256 + lane * 4;
            px0 = *reinterpret_cast<const f32x4*>(src + ncol);
            px1 = *reinterpret_cast<const f32x4*>(src + 1024 + ncol);
            px2 = *reinterpret_cast<const f32x4*>(src + 2048 + ncol);
            px3 = *reinterpret_cast<const f32x4*>(src + 3072 + ncol);
        }
        const int col = cq * 256 + lane * 4;
        #pragma unroll
        for (int i = 0; i < 4; ++i) {
            f32x4 o;
            #pragma unroll
            for (int e = 0; e < 4; ++e)
                o[e] = fmaf(Mr[i*4+3], x3[e],
                        fmaf(Mr[i*4+2], x2[e],
                          fmaf(Mr[i*4+1], x1[e], Mr[i*4+0] * x0[e])));
            __builtin_nontemporal_store(o, reinterpret_cast<f32x4*>(dst + i * 1024 + col));
        }
    }
}

extern "C" void kernel_launch(void* const* d_in, const int* in_sizes, int n_in,
                              void* d_out, int out_size, void* d_ws, size_t ws_size,
                              hipStream_t stream) {
    const float* streams    = (const float*)d_in[0];
    const float* norm_scale = (const float*)d_in[1];
    const float* proj_w     = (const float*)d_in[2];
    const float* proj_b     = (const float*)d_in[3];
    const float* out_scale  = (const float*)d_in[4];
    float* outp = (float*)d_out;

    unsigned int* wbf = (unsigned int*)d_ws;       // 48*4096 bf16 = 393216 B

    scale_weights<<<dim3(192), 256, 0, stream>>>(proj_w, norm_scale, wbf);

    const int n_tok = in_sizes[0] / 4096;          // B*S = 16384
    fused_stream_mix<<<dim3(n_tok / 8), 512, 0, stream>>>(streams,
                                                          (const unsigned short*)wbf,
                                                          proj_b, out_scale, outp);
}

// Round 19
// 146.584 us; speedup vs baseline: 1.3357x; 1.3357x over previous
//
#include <hip/hip_runtime.h>
#include <hip/hip_bf16.h>

#define EPS_F 1e-5f

typedef __bf16 bf16x8 __attribute__((ext_vector_type(8)));
typedef float f32x4 __attribute__((ext_vector_type(4)));

static __device__ __forceinline__ unsigned int pack_bf16x2(float a, float b) {
    union { float f; unsigned int u; } ca, cb;
    ca.f = a; cb.f = b;
    unsigned int ua = (ca.u + 0x7fffu + ((ca.u >> 16) & 1u)) >> 16;
    unsigned int ub = (cb.u + 0x7fffu + ((cb.u >> 16) & 1u)) >> 16;
    return ua | (ub << 16);
}

// ---- setup: wbf[n][k] = bf16(proj_w[n][k] * norm_scale[k]), [48][4096] ----
__global__ void scale_weights(const float* __restrict__ w,
                              const float* __restrict__ ns,
                              unsigned int* __restrict__ wbf)
{
    const int i = (blockIdx.x * 256 + threadIdx.x) * 4;
    const float4 wv = *reinterpret_cast<const float4*>(w + i);
    const float4 nv = *reinterpret_cast<const float4*>(ns + (i & 4095));
    uint2 o;
    o.x = pack_bf16x2(wv.x * nv.x, wv.y * nv.y);
    o.y = pack_bf16x2(wv.z * nv.z, wv.w * nv.w);
    *reinterpret_cast<uint2*>(wbf + (i >> 1)) = o;
}

// ============ Fused: M-projection (MFMA) + 4x4 math + apply, one kernel =====
// R13 (empirical best, 145 us): 512 thr, 16 tokens/block, 1024 blocks,
// 8-way split-K, 4-ks pinned load batches, half-wave phase-3/4, nontemporal
// stores. All structural variants (R14-R18) regressed; this is the floor of
// this design under the 64-VGPR / bare-launch_bounds regime.
__global__ __launch_bounds__(512)
void fused_stream_mix(const float* __restrict__ streams,
                      const unsigned short* __restrict__ wbf,   // scaled bf16 W [48][4096]
                      const float* __restrict__ proj_b,
                      const float* __restrict__ out_scale,
                      float* __restrict__ out)
{
    __shared__ float red[8][3][16][16];   // [kpart][ntile][token][col] = 24 KB
    __shared__ float ssq_red[8][16];      // [kpart][token]

    const int tid  = threadIdx.x;
    const int wv   = tid >> 6;            // wave == K-part
    const int lane = tid & 63;
    const size_t tok0 = (size_t)blockIdx.x * 16;

    // ---------- Phase 2: MFMA projection, 8-way split-K, 4x4 pinned batches ----------
    {
        const int r = lane & 15;          // token row == B column
        const int g = lane >> 4;          // k-subgroup
        const int koff = g * 8;
        const int kbase = wv * 512;       // this wave's K eighth

        const float* ap = streams + (tok0 + r) * 4096 + kbase + koff;
        const unsigned short* wp = wbf + (size_t)r * 4096 + kbase + koff;

        f32x4 acc0 = {0.f, 0.f, 0.f, 0.f};
        f32x4 acc1 = acc0, acc2 = acc0;
        float ssq = 0.f;

        #pragma unroll 1
        for (int p = 0; p < 4; ++p) {
            // batch-issue this pass's 8 A-loads (HBM) + 12 B-loads (L2)
            f32x4 ar[8];
            bf16x8 br[12];
            #pragma unroll
            for (int q = 0; q < 4; ++q) {
                const int ks = p * 4 + q;
                ar[2 * q]     = *reinterpret_cast<const f32x4*>(ap + ks * 32);
                ar[2 * q + 1] = *reinterpret_cast<const f32x4*>(ap + ks * 32 + 4);
                br[3 * q]     = *reinterpret_cast<const bf16x8*>(wp + ks * 32);
                br[3 * q + 1] = *reinterpret_cast<const bf16x8*>(wp + 16 * 4096 + ks * 32);
                br[3 * q + 2] = *reinterpret_cast<const bf16x8*>(wp + 32 * 4096 + ks * 32);
            }
            // keep-alive: forces all 20 loads to issue before any consumption
            asm volatile("" ::
                "v"(ar[0]), "v"(ar[1]), "v"(ar[2]), "v"(ar[3]),
                "v"(ar[4]), "v"(ar[5]), "v"(ar[6]), "v"(ar[7]),
                "v"(br[0]), "v"(br[1]), "v"(br[2]), "v"(br[3]),
                "v"(br[4]), "v"(br[5]), "v"(br[6]), "v"(br[7]),
                "v"(br[8]), "v"(br[9]), "v"(br[10]), "v"(br[11]));

            #pragma unroll
            for (int q = 0; q < 4; ++q) {
                const f32x4 a0 = ar[2 * q], a1 = ar[2 * q + 1];
                ssq = fmaf(a0[0], a0[0], ssq); ssq = fmaf(a0[1], a0[1], ssq);
                ssq = fmaf(a0[2], a0[2], ssq); ssq = fmaf(a0[3], a0[3], ssq);
                ssq = fmaf(a1[0], a1[0], ssq); ssq = fmaf(a1[1], a1[1], ssq);
                ssq = fmaf(a1[2], a1[2], ssq); ssq = fmaf(a1[3], a1[3], ssq);
                bf16x8 a;
                a[0] = (__bf16)a0[0]; a[1] = (__bf16)a0[1]; a[2] = (__bf16)a0[2]; a[3] = (__bf16)a0[3];
                a[4] = (__bf16)a1[0]; a[5] = (__bf16)a1[1]; a[6] = (__bf16)a1[2]; a[7] = (__bf16)a1[3];
                acc0 = __builtin_amdgcn_mfma_f32_16x16x32_bf16(a, br[3 * q],     acc0, 0, 0, 0);
                acc1 = __builtin_amdgcn_mfma_f32_16x16x32_bf16(a, br[3 * q + 1], acc1, 0, 0, 0);
                acc2 = __builtin_amdgcn_mfma_f32_16x16x32_bf16(a, br[3 * q + 2], acc2, 0, 0, 0);
            }
        }

        // ssq: lanes {l, l^16, l^32, l^48} are the 4 k-subgroups of token r
        ssq += __shfl_xor(ssq, 16, 64);
        ssq += __shfl_xor(ssq, 32, 64);
        if (lane < 16) ssq_red[wv][lane] = ssq;

        // D layout: col=lane&15 (=n), row=(lane>>4)*4+reg (=token)
        #pragma unroll
        for (int rr = 0; rr < 4; ++rr) {
            red[wv][0][g * 4 + rr][r] = acc0[rr];
            red[wv][1][g * 4 + rr][r] = acc1[rr];
            red[wv][2][g * 4 + rr][r] = acc2[rr];
        }
    }
    __syncthreads();   // the only barrier

    // ---------- Phase 3+4 setup: half-wave owns token t ----------
    const int t  = wv * 2 + (lane >> 5);  // wave wv -> tokens 2wv, 2wv+1
    const int l5 = lane & 31;
    const float* src = streams + (tok0 + t) * 4096;
    float* dst = out + (tok0 + t) * 4096;

    // issue first phase-4 load batch NOW; phase-3 math (~250 VALU) hides it
    f32x4 px0 = *reinterpret_cast<const f32x4*>(src + l5 * 4);
    f32x4 px1 = *reinterpret_cast<const f32x4*>(src + 1024 + l5 * 4);
    f32x4 px2 = *reinterpret_cast<const f32x4*>(src + 2048 + l5 * 4);
    f32x4 px3 = *reinterpret_cast<const f32x4*>(src + 3072 + l5 * 4);
    asm volatile("" :: "v"(px0), "v"(px1), "v"(px2), "v"(px3));

    // ---------- Phase 3: build M in registers (redundant per half-wave) ----------
    float Mr[16];
    {
        float st = 0.f;
        #pragma unroll
        for (int kp = 0; kp < 8; ++kp) st += ssq_red[kp][t];
        const float invr = rsqrtf(st * (1.f / 4096.f) + EPS_F);

        #define REDUCE_TILE(tile, raw)                                             \
            {                                                                      \
                _Pragma("unroll")                                                  \
                for (int c4 = 0; c4 < 4; ++c4) {                                   \
                    f32x4 s = {0.f, 0.f, 0.f, 0.f};                                \
                    _Pragma("unroll")                                              \
                    for (int kp = 0; kp < 8; ++kp)                                 \
                        s += *reinterpret_cast<const f32x4*>(&red[kp][tile][t][c4 * 4]); \
                    const float4 pb = *reinterpret_cast<const float4*>(&proj_b[tile * 16 + c4 * 4]); \
                    raw[c4*4 + 0] = s[0] * invr + pb.x;                            \
                    raw[c4*4 + 1] = s[1] * invr + pb.y;                            \
                    raw[c4*4 + 2] = s[2] * invr + pb.z;                            \
                    raw[c4*4 + 3] = s[3] * invr + pb.w;                            \
                }                                                                  \
            }

        float c[4] = {0.f, 0.f, 0.f, 0.f};
        {
            float raw[16];
            REDUCE_TILE(0, raw)
            #pragma unroll
            for (int i = 0; i < 4; ++i) {
                const float a0 = raw[i*4+0], a1 = raw[i*4+1], a2 = raw[i*4+2], a3 = raw[i*4+3];
                const float m = fmaxf(fmaxf(a0, a1), fmaxf(a2, a3));
                const float e0 = expf(a0 - m), e1 = expf(a1 - m);
                const float e2 = expf(a2 - m), e3 = expf(a3 - m);
                const float inv = 1.f / (e0 + e1 + e2 + e3);
                c[0] = fmaf(e0, inv, c[0]); c[1] = fmaf(e1, inv, c[1]);
                c[2] = fmaf(e2, inv, c[2]); c[3] = fmaf(e3, inv, c[3]);
            }
            c[0] *= 0.25f; c[1] *= 0.25f; c[2] *= 0.25f; c[3] *= 0.25f;
        }

        float rs[4] = {0.f, 0.f, 0.f, 0.f};
        {
            float raw[16];
            REDUCE_TILE(1, raw)
            #pragma unroll
            for (int j = 0; j < 4; ++j) {
                const float b0 = raw[j], b1 = raw[4+j], b2 = raw[8+j], b3 = raw[12+j];
                const float m = fmaxf(fmaxf(b0, b1), fmaxf(b2, b3));
                const float e0 = expf(b0 - m), e1 = expf(b1 - m);
                const float e2 = expf(b2 - m), e3 = expf(b3 - m);
                const float inv = 1.f / (e0 + e1 + e2 + e3);
                rs[0] = fmaf(e0, inv, rs[0]); rs[1] = fmaf(e1, inv, rs[1]);
                rs[2] = fmaf(e2, inv, rs[2]); rs[3] = fmaf(e3, inv, rs[3]);
            }
        }

        float W[16], Y[16];
        {
            float raw[16];
            REDUCE_TILE(2, raw)
            #pragma unroll
            for (int i = 0; i < 4; ++i)
                #pragma unroll
                for (int j = 0; j < 4; ++j)
                    W[i*4+j] = raw[i*4+j] - raw[j*4+i];
        }
        #pragma unroll
        for (int i = 0; i < 16; ++i) Y[i] = 0.1f * W[i];
        Y[0] += 1.f; Y[5] += 1.f; Y[10] += 1.f; Y[15] += 1.f;
        #pragma unroll
        for (int it = 0; it < 2; ++it) {
            float T1[16];
            #pragma unroll
            for (int i = 0; i < 16; ++i) T1[i] = Y[i];
            T1[0] += 1.f; T1[5] += 1.f; T1[10] += 1.f; T1[15] += 1.f;
            float Yn[16];
            #pragma unroll
            for (int i = 0; i < 4; ++i)
                #pragma unroll
                for (int j = 0; j < 4; ++j) {
                    float s = W[i*4+0] * T1[0*4+j];
                    s = fmaf(W[i*4+1], T1[1*4+j], s);
                    s = fmaf(W[i*4+2], T1[2*4+j], s);
                    s = fmaf(W[i*4+3], T1[3*4+j], s);
                    Yn[i*4+j] = ((i == j) ? 1.f : 0.f) + 0.05f * s;
                }
            #pragma unroll
            for (int i = 0; i < 16; ++i) Y[i] = Yn[i];
        }

        const float os = out_scale[0];
        #pragma unroll
        for (int i = 0; i < 4; ++i)
            #pragma unroll
            for (int j = 0; j < 4; ++j)
                Mr[i*4+j] = Y[i*4+j] + os * rs[i] * c[j];
        #undef REDUCE_TILE
    }

    // ---------- Phase 4: out[t] = M @ streams[t], cache-hot re-read ----------
    #pragma unroll 2
    for (int cq = 0; cq < 8; ++cq) {
        const f32x4 x0 = px0, x1 = px1, x2 = px2, x3 = px3;
        if (cq < 7) {
            const int ncol = (cq + 1) * 128 + l5 * 4;
            px0 = *reinterpret_cast<const f32x4*>(src + ncol);
            px1 = *reinterpret_cast<const f32x4*>(src + 1024 + ncol);
            px2 = *reinterpret_cast<const f32x4*>(src + 2048 + ncol);
            px3 = *reinterpret_cast<const f32x4*>(src + 3072 + ncol);
        }
        const int col = cq * 128 + l5 * 4;
        #pragma unroll
        for (int i = 0; i < 4; ++i) {
            f32x4 o;
            #pragma unroll
            for (int e = 0; e < 4; ++e)
                o[e] = fmaf(Mr[i*4+3], x3[e],
                        fmaf(Mr[i*4+2], x2[e],
                          fmaf(Mr[i*4+1], x1[e], Mr[i*4+0] * x0[e])));
            __builtin_nontemporal_store(o, reinterpret_cast<f32x4*>(dst + i * 1024 + col));
        }
    }
}

extern "C" void kernel_launch(void* const* d_in, const int* in_sizes, int n_in,
                              void* d_out, int out_size, void* d_ws, size_t ws_size,
                              hipStream_t stream) {
    const float* streams    = (const float*)d_in[0];
    const float* norm_scale = (const float*)d_in[1];
    const float* proj_w     = (const float*)d_in[2];
    const float* proj_b     = (const float*)d_in[3];
    const float* out_scale  = (const float*)d_in[4];
    float* outp = (float*)d_out;

    unsigned int* wbf = (unsigned int*)d_ws;       // 48*4096 bf16 = 393216 B

    scale_weights<<<dim3(192), 256, 0, stream>>>(proj_w, norm_scale, wbf);

    const int n_tok = in_sizes[0] / 4096;          // B*S = 16384
    fused_stream_mix<<<dim3(n_tok / 16), 512, 0, stream>>>(streams,
                                                           (const unsigned short*)wbf,
                                                           proj_b, out_scale, outp);
}